// Round 7
// baseline (1106.959 us; speedup 1.0000x reference)
//
#include <hip/hip_runtime.h>
#include <math.h>

#define BB 256
#define TT 512
#define KK 128

typedef float v2f __attribute__((ext_vector_type(2)));

template<int CTRL>
__device__ __forceinline__ int dpp_i(int x) {
  return __builtin_amdgcn_update_dpp(x, x, CTRL, 0xF, 0xF, true);
}
template<int CTRL>
__device__ __forceinline__ float dpp_f(float x) {
  return __int_as_float(dpp_i<CTRL>(__float_as_int(x)));
}
__device__ __forceinline__ float swz16_f(float x) {
  return __int_as_float(__builtin_amdgcn_ds_swizzle(__float_as_int(x), 0x401F));
}
// DPP: 0xB1 quad_perm xor1 (exact), 0x4E quad_perm xor2 (exact),
// 0x141 row_half_mirror (==xor4 once quad-uniform), 0x140 row_mirror (==xor8 once 8-uniform)

__global__ void prep_trans(const float* __restrict__ trans, float* __restrict__ transG) {
  int idx = blockIdx.x * 256 + threadIdx.x;   // 0..16383
  int i = idx >> 7, j = idx & 127;
  transG[j * KK + i] = trans[idx];            // transG[j][i] = trans[i][j]
}

// One wave per recurrence chain. blockIdx < BB: viterbi chain; else forward chain.
__global__ __launch_bounds__(64, 1) void crf_chain(
    const float* __restrict__ logits,     // [B,T,K]
    const int* __restrict__ labels,       // [B,T]
    const int* __restrict__ seq_lens,     // [B]
    const float* __restrict__ trans,      // [K,K]
    float* __restrict__ pred_out,         // [B,T] as float (d_out+1)
    float* __restrict__ negll,            // [B] in ws
    float* __restrict__ ahist,            // [B,T,K] exact viterbi alphas in ws
    const float* __restrict__ transG)     // [K,K] transposed trans in ws
{
  const int l = threadIdx.x;              // 0..63
  const bool isV = blockIdx.x < BB;
  const int b = isV ? (int)blockIdx.x : (int)blockIdx.x - BB;
  const int L = seq_lens[b];
  const int j0 = l * 2;                   // my two adjacent columns

  __shared__ __align__(16) float st[KK];          // state, single buffer (1 wave: DS in-order)
  __shared__ __align__(16) float tl[KK * KK];     // transG staged for backtrace (V only)
  __shared__ unsigned char tags[TT];

  // trans column pair in registers: 128 v2f (raw for V, exp for F)
  v2f tw[KK];
#pragma unroll
  for (int i = 0; i < KK; ++i) {
    v2f w = *(const v2f*)&trans[i * KK + j0];
    if (!isV) { w.x = __expf(w.x); w.y = __expf(w.y); }
    tw[i] = w;
  }

  v2f cur;
  {
    v2f l0 = *(const v2f*)&logits[(size_t)b * TT * KK + j0];
    if (isV) {
      cur = l0;
      *(v2f*)&ahist[(size_t)b * TT * KK + j0] = l0;   // alpha_0
    } else {
      cur = (v2f){__expf(l0.x), __expf(l0.y)};
    }
    *(v2f*)&st[j0] = cur;
  }

  float Cln = 0.0f;
  // emit prefetch, depth 2
  int i1 = (L > 1) ? 1 : 0, i2 = (L > 2) ? 2 : i1;
  v2f emA = *(const v2f*)&logits[((size_t)b * TT + i1) * KK + j0];
  v2f emB = *(const v2f*)&logits[((size_t)b * TT + i2) * KK + j0];

  for (int t = 1; t < L; ++t) {
    int i3 = t + 2; if (i3 > L - 1) i3 = L - 1;
    v2f emC = *(const v2f*)&logits[((size_t)b * TT + i3) * KK + j0];
    const float4* a4p = (const float4*)st;

    if (isV) {
      // ---- max-plus matvec: 128 rows -> my 2 cols (exact IEEE add/max) ----
      v2f c0, c1, c2, c3;
      {
        float4 a4 = a4p[0];
        c0 = (v2f){a4.x, a4.x} + tw[0];
        c1 = (v2f){a4.y, a4.y} + tw[1];
        c2 = (v2f){a4.z, a4.z} + tw[2];
        c3 = (v2f){a4.w, a4.w} + tw[3];
      }
#pragma unroll
      for (int q = 1; q < 32; ++q) {
        float4 a4 = a4p[q];                        // LDS broadcast read
        c0 = __builtin_elementwise_max(c0, (v2f){a4.x, a4.x} + tw[4 * q]);
        c1 = __builtin_elementwise_max(c1, (v2f){a4.y, a4.y} + tw[4 * q + 1]);
        c2 = __builtin_elementwise_max(c2, (v2f){a4.z, a4.z} + tw[4 * q + 2]);
        c3 = __builtin_elementwise_max(c3, (v2f){a4.w, a4.w} + tw[4 * q + 3]);
      }
      v2f m = __builtin_elementwise_max(__builtin_elementwise_max(c0, c1),
                                        __builtin_elementwise_max(c2, c3));
      cur = m + emA;
      *(v2f*)&st[j0] = cur;                        // same-wave DS order: safe
      *(v2f*)&ahist[((size_t)b * TT + t) * KK + j0] = cur;   // fire-and-forget
    } else {
      // ---- sum-product matvec in scaled linear domain ----
      v2f s0 = {0.f, 0.f}, s1 = {0.f, 0.f}, s2 = {0.f, 0.f}, s3 = {0.f, 0.f};
#pragma unroll
      for (int q = 0; q < 32; ++q) {
        float4 a4 = a4p[q];
        s0 += (v2f){a4.x, a4.x} * tw[4 * q];       // pk_fma
        s1 += (v2f){a4.y, a4.y} * tw[4 * q + 1];
        s2 += (v2f){a4.z, a4.z} * tw[4 * q + 2];
        s3 += (v2f){a4.w, a4.w} * tw[4 * q + 3];
      }
      v2f S = (s0 + s1) + (s2 + s3);
      cur.x = S.x * __expf(emA.x);
      cur.y = S.y * __expf(emA.y);
      if ((t & 3) == 0) {                          // renorm: exact pow2 scale
        float wm = fmaxf(cur.x, cur.y);
        wm = fmaxf(wm, dpp_f<0xB1>(wm));
        wm = fmaxf(wm, dpp_f<0x4E>(wm));
        wm = fmaxf(wm, dpp_f<0x141>(wm));
        wm = fmaxf(wm, dpp_f<0x140>(wm));
        wm = fmaxf(wm, swz16_f(wm));
        wm = fmaxf(wm, __shfl_xor(wm, 32));
        int ex = (__float_as_int(wm) >> 23) & 255;
        float r = __int_as_float((254 - ex) << 23);
        Cln += (float)(ex - 127) * 0.6931471805599453f;
        cur.x *= r; cur.y *= r;
      }
      *(v2f*)&st[j0] = cur;
    }
    emA = emB; emB = emC;
  }

  if (isV) {
    // ---- final argmax across lanes (first-index ties) ----
    float v; int idx;
    if (cur.x >= cur.y) { v = cur.x; idx = j0; } else { v = cur.y; idx = j0 + 1; }
#pragma unroll
    for (int mm = 1; mm < 64; mm <<= 1) {
      float ov = __shfl_xor(v, mm);
      int oi = __shfl_xor(idx, mm);
      if (ov > v || (ov == v && oi < idx)) { v = ov; idx = oi; }
    }
    const int last = idx;                          // wave-uniform

    // stage transG into LDS for the serial chase
    {
      const float4* src = (const float4*)transG;
      float4* dst = (float4*)tl;
#pragma unroll 1
      for (int k = l; k < (KK * KK) / 4; k += 64) dst[k] = src[k];
    }
    for (int p = l; p < TT; p += 64) tags[p] = (unsigned char)last;

    // ---- backtrace: recompute path argmaxes from exact alphas ----
    if (L >= 2) {
      int tag = last;
      int t = L - 1;
      while (t >= 1) {
        int n = (t < 4) ? t : 4;
        float2 rows[4];
#pragma unroll
        for (int k = 0; k < 4; ++k)
          if (k < n)
            rows[k] = *(const float2*)&ahist[((size_t)b * TT + (t - 1 - k)) * KK + j0];
#pragma unroll
        for (int k = 0; k < 4; ++k) {
          if (k < n) {
            float2 trow = *(const float2*)&tl[tag * KK + j0];
            float qx = rows[k].x + trow.x;         // bitwise == forward scores
            float qy = rows[k].y + trow.y;
            float M = fmaxf(qx, qy);
            M = fmaxf(M, dpp_f<0xB1>(M));
            M = fmaxf(M, dpp_f<0x4E>(M));
            M = fmaxf(M, dpp_f<0x141>(M));
            M = fmaxf(M, dpp_f<0x140>(M));
            M = fmaxf(M, swz16_f(M));
            M = fmaxf(M, __shfl_xor(M, 32));
            unsigned long long bx = __ballot(qx == M);
            unsigned long long by = __ballot(qy == M);
            int ix = bx ? ((__ffsll(bx) - 1) << 1) : (1 << 20);
            int iy = by ? ((((__ffsll(by) - 1)) << 1) | 1) : (1 << 20);
            tag = (ix < iy) ? ix : iy;             // first-index tie-break
            if (l == 0) tags[t - 1 - k] = (unsigned char)tag;
          }
        }
        t -= n;
      }
    }
    for (int p = l; p < TT; p += 64)
      pred_out[(size_t)b * TT + p] = (float)tags[p];

  } else {
    // ---- log-norm + sequence score ----
    float es = cur.x + cur.y;
    es += dpp_f<0xB1>(es);
    es += dpp_f<0x4E>(es);
    es += dpp_f<0x141>(es);
    es += dpp_f<0x140>(es);
    es += swz16_f(es);
    es += __shfl_xor(es, 32);
    float sc = 0.0f;
    for (int tt2 = l; tt2 < L; tt2 += 64) {
      int lab = labels[b * TT + tt2];
      sc += logits[((size_t)b * TT + tt2) * KK + lab];
      if (tt2 >= 1) sc += trans[labels[b * TT + tt2 - 1] * KK + lab];
    }
#pragma unroll
    for (int mm = 1; mm < 64; mm <<= 1) sc += __shfl_xor(sc, mm);
    if (l == 0) negll[b] = (Cln + logf(es)) - sc;
  }
}

__global__ void crf_loss_reduce(const float* __restrict__ negll, float* __restrict__ out) {
  int tid = threadIdx.x;
  float v = negll[tid];
#pragma unroll
  for (int m = 1; m < 64; m <<= 1) v += __shfl_xor(v, m);
  __shared__ float p[4];
  if ((tid & 63) == 0) p[tid >> 6] = v;
  __syncthreads();
  if (tid == 0) out[0] = p[0] + p[1] + p[2] + p[3];
}

extern "C" void kernel_launch(void* const* d_in, const int* in_sizes, int n_in,
                              void* d_out, int out_size, void* d_ws, size_t ws_size,
                              hipStream_t stream) {
  const float* logits   = (const float*)d_in[0];
  const int*   labels   = (const int*)d_in[1];
  const int*   seq_lens = (const int*)d_in[2];
  const float* trans    = (const float*)d_in[3];
  float* out = (float*)d_out;

  float* negll  = (float*)d_ws;                         // 1 KB
  float* transG = (float*)((char*)d_ws + 1024);         // 64 KB transposed trans
  float* ahist  = (float*)((char*)d_ws + 1024 + 65536); // B*T*K fp32 = 67.1 MB

  prep_trans<<<64, 256, 0, stream>>>(trans, transG);
  crf_chain<<<2 * BB, 64, 0, stream>>>(logits, labels, seq_lens, trans,
                                       out + 1, negll, ahist, transG);
  crf_loss_reduce<<<1, 256, 0, stream>>>(negll, out);
}